// Round 5
// baseline (163.224 us; speedup 1.0000x reference)
//
#include <hip/hip_runtime.h>

// S = J^T K per (p,b); att = softmax over j (per k-column); out = V * att.
// 64 batches; C=64; N=1024. fp32 in/out.
//
// v3 vs v2 (62.6us): occupancy attack.
//  - KTW=64 -> grid 1024 (4 WG/CU); 4 waves split 2x2 over (j-half, k-half);
//    cross-wave U/Z reduction in epilogue via LDS.
//  - LDS union: K-stage region (18.4KB, dead after register hoist) aliased with
//    J/V regions -> 37,888 B/WG -> LDS allows 4 WG/CU (was 61.4KB -> 2).
//  - K fragments pinned in registers via asm "+v" (v2's hoist was silently
//    rematerialized: VGPR_Count=88 < the 96 needed -> LDS reads stayed in loop).
//  - s_setprio(1) around MFMA clusters (T5): 4 WGs/CU now give phase diversity.
//  - __launch_bounds__(256,4): cap 128 VGPR (est. peak ~125).

typedef short bf16x8 __attribute__((ext_vector_type(8)));
typedef short bf16x4 __attribute__((ext_vector_type(4)));
typedef float f32x4  __attribute__((ext_vector_type(4)));

#define NTOK 1024
#define CH   64
#define KTW  64          // k-columns per WG
#define JTILE 64         // j-rows per iteration
#define NIT  (NTOK / JTILE)
#define SJK  72          // row stride (shorts) for transposed J/K and V tiles
#define SP   40          // row stride for per-wave P tile

__device__ __forceinline__ unsigned short f2bf_rne(float x) {
  unsigned int u = __float_as_uint(x);
  u += 0x7FFFu + ((u >> 16) & 1u);
  return (unsigned short)(u >> 16);
}

#define MFMA(a,b,c) __builtin_amdgcn_mfma_f32_16x16x32_bf16((a),(b),(c),0,0,0)

__global__ __launch_bounds__(256, 4) void attn_v3(
    const float* __restrict__ Kg, const float* __restrict__ Jg,
    const float* __restrict__ Vg, float* __restrict__ Og) {
  // LDS union, 37,888 B total:
  //  [0,9216)      Kh (prologue)  /  Jh (loop)   / Ured+Zred (epilogue)
  //  [9216,18432)  Kl (prologue)  /  Jl (loop)
  //  [18432,27648) Vt [64][72]
  //  [27648,37888) P  [4 waves][32][40]
  __shared__ __align__(16) unsigned char LDSBUF[37888];
  unsigned short (*KhS)[SJK] = (unsigned short (*)[SJK])(LDSBUF);
  unsigned short (*KlS)[SJK] = (unsigned short (*)[SJK])(LDSBUF + 9216);
  unsigned short (*JhS)[SJK] = (unsigned short (*)[SJK])(LDSBUF);
  unsigned short (*JlS)[SJK] = (unsigned short (*)[SJK])(LDSBUF + 9216);
  unsigned short (*VtS)[SJK] = (unsigned short (*)[SJK])(LDSBUF + 18432);

  const int tid  = threadIdx.x;
  const int lane = tid & 63;
  const int wave = tid >> 6;
  const int wk   = wave & 1;    // k-half
  const int wj   = wave >> 1;   // j-half
  const int l15  = lane & 15;
  const int l4   = lane >> 4;

  unsigned short (*PtS)[SP] = (unsigned short (*)[SP])(LDSBUF + 27648 + wave * 2560);

  const int bid   = blockIdx.x;
  const int batch = bid & 63;      // bid%8 == batch%8 -> same-batch WGs share an XCD
  const int ktile = bid >> 6;      // 0..15
  const int k0    = ktile * KTW;
  const size_t base = (size_t)batch * (CH * NTOK);
  const float* Kp = Kg + base;
  const float* Jp = Jg + base;
  const float* Vp = Vg + base;
  float*       Op = Og + base;

  // staging geometry: J/K: 2 tasks/thread, task t: row-block oct = (tid>>6)+4t, col tid&63
  const int jJ   = tid & 63;
  const int octJ = tid >> 6;                    // 0..3
  const float* srcJ = Jp + (size_t)(octJ * 8) * NTOK + jJ;
  // V: 4 float4/thread: row c0v, cols jc0..jc0+15
  const int c0v = tid >> 2;
  const int jc0 = (tid & 3) * 16;
  const float* srcV = Vp + (size_t)c0v * NTOK + jc0;

  float  jr[2][8];
  float4 vr[4];

  auto issueJ = [&](int j0) {
    #pragma unroll
    for (int t = 0; t < 2; ++t)
      #pragma unroll
      for (int r = 0; r < 8; ++r)
        jr[t][r] = srcJ[(size_t)(t * 32 + r) * NTOK + j0];
  };
  auto issueV = [&](int j0) {
    #pragma unroll
    for (int q = 0; q < 4; ++q)
      vr[q] = *(const float4*)(srcV + j0 + q * 4);
  };
  auto stageJ = [&]() {
    #pragma unroll
    for (int t = 0; t < 2; ++t) {
      bf16x8 hv, lv;
      #pragma unroll
      for (int r = 0; r < 8; ++r) {
        unsigned int u = __float_as_uint(jr[t][r]);
        hv[r] = (short)(u >> 16);
        float hf = __uint_as_float(u & 0xFFFF0000u);
        lv[r] = (short)(__float_as_uint(jr[t][r] - hf) >> 16);
      }
      *(bf16x8*)&JhS[jJ][(octJ + 4 * t) * 8] = hv;
      *(bf16x8*)&JlS[jJ][(octJ + 4 * t) * 8] = lv;
    }
  };
  auto stageV = [&]() {
    #pragma unroll
    for (int q = 0; q < 4; ++q) {
      bf16x4 w;
      w[0] = (short)f2bf_rne(vr[q].x); w[1] = (short)f2bf_rne(vr[q].y);
      w[2] = (short)f2bf_rne(vr[q].z); w[3] = (short)f2bf_rne(vr[q].w);
      *(bf16x4*)&VtS[c0v][jc0 + q * 4] = w;
    }
  };

  // ---- prefetch iter-0 J/V (in flight under K staging) ----
  issueJ(0);
  issueV(0);

  // ---- stage K tile: transpose [c][k]->[k][c], trunc hi/lo split ----
  #pragma unroll
  for (int t = 0; t < 2; ++t) {
    const float* src = Kp + (size_t)((octJ + 4 * t) * 8) * NTOK + k0 + jJ;
    bf16x8 hv, lv;
    #pragma unroll
    for (int r = 0; r < 8; ++r) {
      float v = src[(size_t)r * NTOK];
      unsigned int u = __float_as_uint(v);
      hv[r] = (short)(u >> 16);
      float hf = __uint_as_float(u & 0xFFFF0000u);
      lv[r] = (short)(__float_as_uint(v - hf) >> 16);
    }
    *(bf16x8*)&KhS[jJ][(octJ + 4 * t) * 8] = hv;
    *(bf16x8*)&KlS[jJ][(octJ + 4 * t) * 8] = lv;
  }
  __syncthreads();

  // ---- hoist this wave's K fragments to registers; PIN so they can't be
  //      rematerialized from (soon-overwritten) LDS ----
  bf16x8 kbh[2][2], kbl[2][2];     // [ks][cd]
  #pragma unroll
  for (int ks = 0; ks < 2; ++ks)
    #pragma unroll
    for (int cd = 0; cd < 2; ++cd) {
      kbh[ks][cd] = *(const bf16x8*)&KhS[wk * 32 + ks * 16 + l15][cd * 32 + l4 * 8];
      kbl[ks][cd] = *(const bf16x8*)&KlS[wk * 32 + ks * 16 + l15][cd * 32 + l4 * 8];
      asm volatile("" : "+v"(kbh[ks][cd]), "+v"(kbl[ks][cd]));
    }
  __syncthreads();   // hoist reads done; K region now reusable for J

  f32x4 U[4][2];     // [c-subtile][k-subtile], this wave's (wj-partial) accumulator
  #pragma unroll
  for (int a = 0; a < 4; ++a)
    #pragma unroll
    for (int b = 0; b < 2; ++b) U[a][b] = (f32x4){0.f, 0.f, 0.f, 0.f};
  float zacc0 = 0.f, zacc1 = 0.f;

  #pragma unroll 1
  for (int it = 0; it < NIT; ++it) {
    stageJ();
    stageV();
    __syncthreads();
    if (it + 1 < NIT) issueJ((it + 1) * JTILE);   // in flight across compute

    // ---- QK^T (split-bf16: hh + hl + lh) ----
    f32x4 S[2][2];
    #pragma unroll
    for (int a = 0; a < 2; ++a)
      #pragma unroll
      for (int b = 0; b < 2; ++b) S[a][b] = (f32x4){0.f, 0.f, 0.f, 0.f};
    __builtin_amdgcn_s_setprio(1);
    #pragma unroll
    for (int cd = 0; cd < 2; ++cd) {
      const int co = cd * 32 + l4 * 8;
      bf16x8 ah0 = *(const bf16x8*)&JhS[wj * 32 + l15][co];
      bf16x8 ah1 = *(const bf16x8*)&JhS[wj * 32 + 16 + l15][co];
      bf16x8 al0 = *(const bf16x8*)&JlS[wj * 32 + l15][co];
      bf16x8 al1 = *(const bf16x8*)&JlS[wj * 32 + 16 + l15][co];
      #pragma unroll
      for (int ks = 0; ks < 2; ++ks) {
        S[0][ks] = MFMA(ah0, kbh[ks][cd], S[0][ks]);
        S[0][ks] = MFMA(ah0, kbl[ks][cd], S[0][ks]);
        S[0][ks] = MFMA(al0, kbh[ks][cd], S[0][ks]);
        S[1][ks] = MFMA(ah1, kbh[ks][cd], S[1][ks]);
        S[1][ks] = MFMA(ah1, kbl[ks][cd], S[1][ks]);
        S[1][ks] = MFMA(al1, kbh[ks][cd], S[1][ks]);
      }
    }
    __builtin_amdgcn_s_setprio(0);

    // ---- exp (unnormalized), Z partials, pack, stash P (per-wave) ----
    #pragma unroll
    for (int js = 0; js < 2; ++js)
      #pragma unroll
      for (int ks = 0; ks < 2; ++ks) {
        f32x4 s = S[js][ks];
        float e0 = __expf(s[0]);
        float e1 = __expf(s[1]);
        float e2 = __expf(s[2]);
        float e3 = __expf(s[3]);
        if (ks == 0) zacc0 += (e0 + e1) + (e2 + e3);
        else         zacc1 += (e0 + e1) + (e2 + e3);
        bf16x4 pv;
        pv[0] = (short)f2bf_rne(e0); pv[1] = (short)f2bf_rne(e1);
        pv[2] = (short)f2bf_rne(e2); pv[3] = (short)f2bf_rne(e3);
        *(bf16x4*)&PtS[ks * 16 + l15][js * 16 + l4 * 4] = pv;
      }

    if (it + 1 < NIT) issueV((it + 1) * JTILE);   // reuses dead S registers

    // ---- PV: U[c, wk-half] += V[c, wave's j-slice] * P ----
    bf16x8 pb0 = *(const bf16x8*)&PtS[l15][l4 * 8];
    bf16x8 pb1 = *(const bf16x8*)&PtS[16 + l15][l4 * 8];
    __builtin_amdgcn_s_setprio(1);
    #pragma unroll
    for (int ct = 0; ct < 4; ++ct) {
      bf16x8 av = *(const bf16x8*)&VtS[ct * 16 + l15][wj * 32 + l4 * 8];
      U[ct][0] = MFMA(av, pb0, U[ct][0]);
      U[ct][1] = MFMA(av, pb1, U[ct][1]);
    }
    __builtin_amdgcn_s_setprio(0);
    __syncthreads();   // compute done reading J/V before next stage overwrites
  }

  // ---- epilogue: reduce Z within wave, then U/Z across wj pair via LDS ----
  float z0 = zacc0; z0 += __shfl_xor(z0, 16); z0 += __shfl_xor(z0, 32);
  float z1 = zacc1; z1 += __shfl_xor(z1, 16); z1 += __shfl_xor(z1, 32);

  float* UL = (float*)(LDSBUF);           // [2 wk][64 c][32 k] = 16384 B
  float* ZL = (float*)(LDSBUF + 16384);   // [2 wk][32 k]
  if (wj == 1) {
    #pragma unroll
    for (int ct = 0; ct < 4; ++ct)
      #pragma unroll
      for (int ks = 0; ks < 2; ++ks)
        #pragma unroll
        for (int r = 0; r < 4; ++r)
          UL[((size_t)wk * 64 + ct * 16 + l4 * 4 + r) * 32 + ks * 16 + l15] = U[ct][ks][r];
    if (lane < 16) {
      ZL[wk * 32 + l15]      = z0;
      ZL[wk * 32 + 16 + l15] = z1;
    }
  }
  __syncthreads();
  if (wj == 0) {
    z0 += ZL[wk * 32 + l15];
    z1 += ZL[wk * 32 + 16 + l15];
    const float rz0 = 1.0f / z0;
    const float rz1 = 1.0f / z1;
    #pragma unroll
    for (int ct = 0; ct < 4; ++ct)
      #pragma unroll
      for (int ks = 0; ks < 2; ++ks)
        #pragma unroll
        for (int r = 0; r < 4; ++r) {
          const int c = ct * 16 + l4 * 4 + r;
          float u = U[ct][ks][r] + UL[((size_t)wk * 64 + c) * 32 + ks * 16 + l15];
          Op[(size_t)c * NTOK + k0 + wk * 32 + ks * 16 + l15] = u * (ks ? rz1 : rz0);
        }
  }
}

extern "C" void kernel_launch(void* const* d_in, const int* in_sizes, int n_in,
                              void* d_out, int out_size, void* d_ws, size_t ws_size,
                              hipStream_t stream) {
  const float* Kg = (const float*)d_in[0];
  const float* Jg = (const float*)d_in[1];
  const float* Vg = (const float*)d_in[2];
  float* Og = (float*)d_out;
  // 16 ktiles x 64 batches; bid = ktile*64 + batch keeps a batch's 16 WGs on one XCD.
  attn_v3<<<dim3(1024), dim3(256), 0, stream>>>(Kg, Jg, Vg, Og);
}

// Round 6
// 125.739 us; speedup vs baseline: 1.2981x; 1.2981x over previous
//
#include <hip/hip_runtime.h>

// S = J^T K per (p,b); att = softmax over j (per k-column); out = V * att.
// 64 batches; C=64; N=1024. fp32 in/out.
//
// v4 vs v2 (62.6us) — same proven indexing (KTW=128, 4 waves k-split, grid 512,
// 2 WG/CU), attacking the two measured costs:
//  - v3 lesson: occupancy push caused 64-VGPR spills (WRITE_SIZE 16->37MB).
//    Here: __launch_bounds__(256,2) keeps the 256-VGPR budget; K fragments
//    pinned via asm "+v" (32 VGPR) -> kills the 8 rematerialized b128
//    LDS reads/wave/iter that v2's VGPR_Count=88 proved were still there.
//  - Double-buffered J/V in the unused LDS headroom (76.8KB of the 80KB/WG
//    budget at 2 WG/CU): stage tile it+1 at END of body -> ONE barrier/iter
//    (was 2) and no serial stage->compute phase.
//  - Stride tuning: SJK 72->76 (fragment reads max 2-way conflict, was 4-way),
//    SV/SP 40->36 (16 distinct banks across l15, was l15=0/8 collision).

typedef short bf16x8 __attribute__((ext_vector_type(8)));
typedef short bf16x4 __attribute__((ext_vector_type(4)));
typedef float f32x4  __attribute__((ext_vector_type(4)));

#define NTOK 1024
#define CH   64
#define KTW  128   // k-columns per WG
#define JTILE 32   // j-rows per iteration
#define NIT  (NTOK / JTILE)
#define SJK  76    // stride (shorts) for transposed J/K tiles
#define SV   36    // stride for V tiles
#define SP   36    // stride for per-wave P tiles

__device__ __forceinline__ unsigned short f2bf_rne(float x) {
  unsigned int u = __float_as_uint(x);
  u += 0x7FFFu + ((u >> 16) & 1u);
  return (unsigned short)(u >> 16);
}

#define MFMA(a,b,c) __builtin_amdgcn_mfma_f32_16x16x32_bf16((a),(b),(c),0,0,0)

__global__ __launch_bounds__(256, 2) void attn_v4(
    const float* __restrict__ Kg, const float* __restrict__ Jg,
    const float* __restrict__ Vg, float* __restrict__ Og) {
  // LDS: K 2*19456 + J 2*9728 + V 9216 + P 9216 = 76,800 B (2 WG/CU)
  __shared__ unsigned short KhS[KTW][SJK];
  __shared__ unsigned short KlS[KTW][SJK];
  __shared__ unsigned short JhS[2][JTILE][SJK];
  __shared__ unsigned short JlS[2][JTILE][SJK];
  __shared__ unsigned short VtS[2][CH][SV];
  __shared__ unsigned short PtS[4][JTILE][SP];

  const int tid  = threadIdx.x;
  const int lane = tid & 63;
  const int wave = tid >> 6;
  const int l15  = lane & 15;
  const int l4   = lane >> 4;

  const int bid   = blockIdx.x;
  const int batch = bid & 63;      // bid%8 == batch%8 -> same-batch WGs share an XCD
  const int ktile = bid >> 6;      // 0..7
  const int k0    = ktile * KTW;
  const size_t base = (size_t)batch * (CH * NTOK);
  const float* Kp = Kg + base;
  const float* Jp = Jg + base;
  const float* Vp = Vg + base;
  float*       Op = Og + base;

  // staging geometry (v2-proven): J: 8 octs x 32 j, 1 task/thread
  const int jJ   = tid & 31;
  const int octJ = tid >> 5;
  const float* srcJ = Jp + (size_t)(octJ * 8) * NTOK + jJ;
  // V: rows c0 and c0+32, 4-wide column quad
  const int c0  = tid >> 3;
  const int jq0 = tid & 7;
  const float* srcV = Vp + (size_t)c0 * NTOK + jq0 * 4;

  float  jr[8];
  float4 vr[2];

  auto issueJV = [&](int j0) {
    #pragma unroll
    for (int r = 0; r < 8; ++r) jr[r] = srcJ[(size_t)r * NTOK + j0];
    vr[0] = *(const float4*)(srcV + j0);
    vr[1] = *(const float4*)(srcV + (size_t)32 * NTOK + j0);
  };
  auto stageJV = [&](int buf) {
    bf16x8 hv, lv;
    #pragma unroll
    for (int r = 0; r < 8; ++r) {
      unsigned int u = __float_as_uint(jr[r]);
      hv[r] = (short)(u >> 16);
      float hf = __uint_as_float(u & 0xFFFF0000u);
      lv[r] = (short)(__float_as_uint(jr[r] - hf) >> 16);
    }
    *(bf16x8*)&JhS[buf][jJ][octJ * 8] = hv;
    *(bf16x8*)&JlS[buf][jJ][octJ * 8] = lv;
    bf16x4 w0, w1;
    w0[0] = (short)f2bf_rne(vr[0].x); w0[1] = (short)f2bf_rne(vr[0].y);
    w0[2] = (short)f2bf_rne(vr[0].z); w0[3] = (short)f2bf_rne(vr[0].w);
    w1[0] = (short)f2bf_rne(vr[1].x); w1[1] = (short)f2bf_rne(vr[1].y);
    w1[2] = (short)f2bf_rne(vr[1].z); w1[3] = (short)f2bf_rne(vr[1].w);
    *(bf16x4*)&VtS[buf][c0][jq0 * 4]      = w0;
    *(bf16x4*)&VtS[buf][c0 + 32][jq0 * 4] = w1;
  };

  // ---- prologue: iter-0 J/V in flight under K staging ----
  issueJV(0);

  // stage K tile: transpose [c][k]->[k][c], trunc hi/lo split (one-time)
  #pragma unroll
  for (int i = 0; i < 4; ++i) {
    int task = i * 256 + tid;
    int k    = task & (KTW - 1);
    int oct  = task >> 7;
    const float* src = Kp + (size_t)(oct * 8) * NTOK + k0 + k;
    bf16x8 hv, lv;
    #pragma unroll
    for (int r = 0; r < 8; ++r) {
      float v = src[(size_t)r * NTOK];
      unsigned int u = __float_as_uint(v);
      hv[r] = (short)(u >> 16);
      float hf = __uint_as_float(u & 0xFFFF0000u);
      lv[r] = (short)(__float_as_uint(v - hf) >> 16);
    }
    *(bf16x8*)&KhS[k][oct * 8] = hv;
    *(bf16x8*)&KlS[k][oct * 8] = lv;
  }
  __syncthreads();

  // hoist this wave's K fragments to registers; pin so they stay there.
  // (K LDS region is never overwritten, so correctness never depends on the
  //  pin — it only prevents per-iter rematerialized reads.)
  bf16x8 kbh[2][2], kbl[2][2];     // [ks][cd]
  #pragma unroll
  for (int ks = 0; ks < 2; ++ks)
    #pragma unroll
    for (int cd = 0; cd < 2; ++cd) {
      kbh[ks][cd] = *(const bf16x8*)&KhS[wave * 32 + ks * 16 + l15][cd * 32 + l4 * 8];
      kbl[ks][cd] = *(const bf16x8*)&KlS[wave * 32 + ks * 16 + l15][cd * 32 + l4 * 8];
      asm volatile("" : "+v"(kbh[ks][cd]), "+v"(kbl[ks][cd]));
    }

  stageJV(0);          // tile 0 into buf 0
  __syncthreads();

  f32x4 U[4][2];
  #pragma unroll
  for (int a = 0; a < 4; ++a)
    #pragma unroll
    for (int b = 0; b < 2; ++b) U[a][b] = (f32x4){0.f, 0.f, 0.f, 0.f};
  float zacc0 = 0.f, zacc1 = 0.f;

  int cur = 0;
  #pragma unroll 1
  for (int it = 0; it < NIT; ++it) {
    if (it + 1 < NIT) issueJV((it + 1) * JTILE);   // in flight under compute

    // ---- QK^T (split-bf16: hh + hl + lh), K from pinned registers ----
    f32x4 S[2][2];
    #pragma unroll
    for (int a = 0; a < 2; ++a)
      #pragma unroll
      for (int b = 0; b < 2; ++b) S[a][b] = (f32x4){0.f, 0.f, 0.f, 0.f};
    __builtin_amdgcn_s_setprio(1);
    #pragma unroll
    for (int cd = 0; cd < 2; ++cd) {
      const int co = cd * 32 + l4 * 8;
      bf16x8 ah0 = *(const bf16x8*)&JhS[cur][l15][co];
      bf16x8 ah1 = *(const bf16x8*)&JhS[cur][l15 + 16][co];
      bf16x8 al0 = *(const bf16x8*)&JlS[cur][l15][co];
      bf16x8 al1 = *(const bf16x8*)&JlS[cur][l15 + 16][co];
      #pragma unroll
      for (int ks = 0; ks < 2; ++ks) {
        S[0][ks] = MFMA(ah0, kbh[ks][cd], S[0][ks]);
        S[0][ks] = MFMA(ah0, kbl[ks][cd], S[0][ks]);
        S[0][ks] = MFMA(al0, kbh[ks][cd], S[0][ks]);
        S[1][ks] = MFMA(ah1, kbh[ks][cd], S[1][ks]);
        S[1][ks] = MFMA(ah1, kbl[ks][cd], S[1][ks]);
        S[1][ks] = MFMA(al1, kbh[ks][cd], S[1][ks]);
      }
    }
    __builtin_amdgcn_s_setprio(0);

    // ---- exp (unnormalized), Z partials, pack, stash P (per-wave region) ----
    #pragma unroll
    for (int js = 0; js < 2; ++js)
      #pragma unroll
      for (int ks = 0; ks < 2; ++ks) {
        f32x4 s = S[js][ks];
        float e0 = __expf(s[0]);
        float e1 = __expf(s[1]);
        float e2 = __expf(s[2]);
        float e3 = __expf(s[3]);
        if (ks == 0) zacc0 += (e0 + e1) + (e2 + e3);
        else         zacc1 += (e0 + e1) + (e2 + e3);
        bf16x4 pv;
        pv[0] = (short)f2bf_rne(e0); pv[1] = (short)f2bf_rne(e1);
        pv[2] = (short)f2bf_rne(e2); pv[3] = (short)f2bf_rne(e3);
        *(bf16x4*)&PtS[wave][ks * 16 + l15][js * 16 + l4 * 4] = pv;
      }

    // ---- PV: U[c,k] += V[c,j] * P[j,k] ----
    bf16x8 pb0 = *(const bf16x8*)&PtS[wave][l15][l4 * 8];
    bf16x8 pb1 = *(const bf16x8*)&PtS[wave][16 + l15][l4 * 8];
    __builtin_amdgcn_s_setprio(1);
    #pragma unroll
    for (int ct = 0; ct < 4; ++ct) {
      bf16x8 av = *(const bf16x8*)&VtS[cur][ct * 16 + l15][l4 * 8];
      U[ct][0] = MFMA(av, pb0, U[ct][0]);
      U[ct][1] = MFMA(av, pb1, U[ct][1]);
    }
    __builtin_amdgcn_s_setprio(0);

    // ---- stage next tile into the other buffer; single barrier per iter ----
    if (it + 1 < NIT) stageJV(cur ^ 1);
    __syncthreads();
    cur ^= 1;
  }

  // ---- epilogue: finish Z reduction, normalize, store (v2-verified) ----
  float z0 = zacc0; z0 += __shfl_xor(z0, 16); z0 += __shfl_xor(z0, 32);
  float z1 = zacc1; z1 += __shfl_xor(z1, 16); z1 += __shfl_xor(z1, 32);
  const float rz0 = 1.0f / z0;
  const float rz1 = 1.0f / z1;
  const int kbase = k0 + wave * 32;
  #pragma unroll
  for (int ct = 0; ct < 4; ++ct)
    #pragma unroll
    for (int r = 0; r < 4; ++r) {
      int c = ct * 16 + l4 * 4 + r;
      Op[(size_t)c * NTOK + kbase + l15]      = U[ct][0][r] * rz0;
      Op[(size_t)c * NTOK + kbase + 16 + l15] = U[ct][1][r] * rz1;
    }
}

extern "C" void kernel_launch(void* const* d_in, const int* in_sizes, int n_in,
                              void* d_out, int out_size, void* d_ws, size_t ws_size,
                              hipStream_t stream) {
  const float* Kg = (const float*)d_in[0];
  const float* Jg = (const float*)d_in[1];
  const float* Vg = (const float*)d_in[2];
  float* Og = (float*)d_out;
  // 8 ktiles x 64 batches; bid = ktile*64 + batch keeps a batch's 8 WGs on one XCD.
  attn_v4<<<dim3(512), dim3(256), 0, stream>>>(Kg, Jg, Vg, Og);
}